// Round 5
// baseline (123.163 us; speedup 1.0000x reference)
//
#include <hip/hip_runtime.h>
#include <stdint.h>

typedef short short8 __attribute__((ext_vector_type(8)));
typedef float floatx4 __attribute__((ext_vector_type(4)));
typedef __attribute__((address_space(3))) char lds_char;
typedef const __attribute__((address_space(1))) void* gbl_cptr;

#define BIAS 8.0f

__device__ __forceinline__ unsigned short f2bf(float f) {
    unsigned int u = __float_as_uint(f);
    unsigned int r = (u + 0x7FFFu + ((u >> 16) & 1u)) >> 16;   // RNE
    return (unsigned short)r;
}

// ---------------- kernel 0: W -> bf16(-w) in MFMA-B-fragment order, + zero loss slot
__global__ void vq_prep(const float* __restrict__ W, unsigned short* __restrict__ Wsw,
                        float* __restrict__ out0) {
    const int s = blockIdx.x * 256 + threadIdx.x;      // 32768 slots
    const int T = s >> 7;
    const int h = (s >> 6) & 1;
    const int l = s & 63;
    const int code = T * 16 + (l & 15);
    const float* src = W + code * 64 + h * 32 + (l >> 4) * 8;
    const floatx4* sp = (const floatx4*)src;
    floatx4 f0 = sp[0], f1 = sp[1];
    short8 fr;
    fr[0] = (short)f2bf(-f0[0]); fr[1] = (short)f2bf(-f0[1]);
    fr[2] = (short)f2bf(-f0[2]); fr[3] = (short)f2bf(-f0[3]);
    fr[4] = (short)f2bf(-f1[0]); fr[5] = (short)f2bf(-f1[1]);
    fr[6] = (short)f2bf(-f1[2]); fr[7] = (short)f2bf(-f1[3]);
    ((short8*)Wsw)[s] = fr;
    if (s == 0) *out0 = 0.0f;
}

// ---- DMA one 4KB group (4 chunks x 64 lanes x 16B) global -> private LDS buffer.
#define STAGE(lbuf, gsrc) do {                                                              \
    const char* _g = (gsrc);                                                                \
    __builtin_amdgcn_global_load_lds((gbl_cptr)(_g),                                        \
        (__attribute__((address_space(3))) void*)((lbuf)),        16, 0, 0);                \
    __builtin_amdgcn_global_load_lds((gbl_cptr)(_g + 1024),                                 \
        (__attribute__((address_space(3))) void*)((lbuf) + 1024), 16, 0, 0);                \
    __builtin_amdgcn_global_load_lds((gbl_cptr)(_g + 2048),                                 \
        (__attribute__((address_space(3))) void*)((lbuf) + 2048), 16, 0, 0);                \
    __builtin_amdgcn_global_load_lds((gbl_cptr)(_g + 3072),                                 \
        (__attribute__((address_space(3))) void*)((lbuf) + 3072), 16, 0, 0);                \
} while (0)

#define VMWAIT(N) asm volatile("s_waitcnt vmcnt(" #N ")" ::: "memory")

// BODY: ds_read 4x16B -> lgkmcnt(0) -> sched_barrier(0x6): VALU|SALU from the
// PREVIOUS body may drift across to fill the wait; MFMA (0x8) stays fenced
// (rule 18), DS/VMEM stay put (exact counting). setprio(1) elevates the MFMA
// cluster (T5 - waves here are barrier-free and phase-staggered).
// Per mt: 2 chained MFMAs per tile, both tiles folded with nested min
// (-> v_min3_u32), live acc = 8 VGPR only.
#define BODY(off, kk0) do {                                                        \
    short8 c0, c1, c2, c3;                                                         \
    asm volatile("ds_read_b128 %0, %1"             : "=v"(c0) : "v"(off));         \
    asm volatile("ds_read_b128 %0, %1 offset:1024" : "=v"(c1) : "v"(off));         \
    asm volatile("ds_read_b128 %0, %1 offset:2048" : "=v"(c2) : "v"(off));         \
    asm volatile("ds_read_b128 %0, %1 offset:3072" : "=v"(c3) : "v"(off));         \
    asm volatile("s_waitcnt lgkmcnt(0)" ::: "memory");                             \
    __builtin_amdgcn_sched_barrier(0x0006);                                        \
    const unsigned kkA = (kk0);                                                    \
    const unsigned kkB = (kk0) + 16u;                                              \
    __builtin_amdgcn_s_setprio(1);                                                 \
    _Pragma("unroll")                                                              \
    for (int mt = 0; mt < 4; ++mt) {                                               \
        floatx4 aA = __builtin_amdgcn_mfma_f32_16x16x32_bf16(afrag[mt][0], c0, bias4, 0, 0, 0); \
        aA = __builtin_amdgcn_mfma_f32_16x16x32_bf16(afrag[mt][1], c1, aA, 0, 0, 0);            \
        floatx4 aB = __builtin_amdgcn_mfma_f32_16x16x32_bf16(afrag[mt][0], c2, bias4, 0, 0, 0); \
        aB = __builtin_amdgcn_mfma_f32_16x16x32_bf16(afrag[mt][1], c3, aB, 0, 0, 0);            \
        _Pragma("unroll")                                                          \
        for (int r = 0; r < 4; ++r) {                                              \
            unsigned pA = __float_as_uint(aA[r]) | kkA;                            \
            unsigned pB = __float_as_uint(aB[r]) | kkB;                            \
            unsigned m = minpk[mt][r];                                             \
            m = m < pA ? m : pA;                                                   \
            m = m < pB ? m : pB;   /* nested min -> v_min3_u32 */                  \
            minpk[mt][r] = m;                                                      \
        }                                                                          \
    }                                                                              \
    __builtin_amdgcn_s_setprio(0);                                                 \
} while (0)

// ---------------- kernel 1: block = 64 rows x 4 waves (one codegroup each).
// B-stream via global_load_lds into per-wave private triple-buffered LDS
// (no barriers in the K-loop; in-flight data lives in the memory system).
__launch_bounds__(256)
__global__ void vq_main(const float* __restrict__ z, const float* __restrict__ W,
                        const unsigned short* __restrict__ Wsw, float* __restrict__ out) {
    __shared__ unsigned int pk_lds[256];   // [wave][local row 0..63]
    __shared__ float ls[4];
    __shared__ __attribute__((aligned(1024))) char bstage[4][3][4096];  // 48 KB

    const int tid  = threadIdx.x;
    const int lane = tid & 63;
    const int cg   = tid >> 6;      // wave = code group (1024 codes each)
    const int l15  = lane & 15;
    const int lq   = lane >> 4;
    const int rowbase = blockIdx.x * 64;

    // ---- A fragments: the block's 64 rows x 64 k as bf16 (32 VGPR)
    short8 afrag[4][2];
    #pragma unroll
    for (int mt = 0; mt < 4; ++mt) {
        const float* zp = z + (rowbase + mt * 16 + l15) * 64 + lq * 8;
        #pragma unroll
        for (int h = 0; h < 2; ++h) {
            const floatx4* p = (const floatx4*)(zp + h * 32);
            floatx4 f0 = p[0], f1 = p[1];
            short8 fr;
            fr[0] = (short)f2bf(f0[0]); fr[1] = (short)f2bf(f0[1]);
            fr[2] = (short)f2bf(f0[2]); fr[3] = (short)f2bf(f0[3]);
            fr[4] = (short)f2bf(f1[0]); fr[5] = (short)f2bf(f1[1]);
            fr[6] = (short)f2bf(f1[2]); fr[7] = (short)f2bf(f1[3]);
            afrag[mt][h] = fr;
        }
    }

    const floatx4 bias4 = {BIAS, BIAS, BIAS, BIAS};
    unsigned int minpk[4][4];
    #pragma unroll
    for (int mt = 0; mt < 4; ++mt)
        #pragma unroll
        for (int r = 0; r < 4; ++r) minpk[mt][r] = 0xFFFFFFFFu;

    // ---- LDS buffer bases (wave-uniform)
    unsigned baseA = (unsigned)(unsigned long long)(void*)&bstage[cg][0][0];
    baseA = __builtin_amdgcn_readfirstlane(baseA);
    lds_char* bufA = (lds_char*)(unsigned long long)baseA;
    lds_char* bufB = bufA + 4096;
    lds_char* bufC = bufA + 8192;
    const unsigned l16  = (unsigned)lane * 16u;
    const unsigned offA = baseA + l16;          // per-lane ds_read addresses
    const unsigned offB = offA + 4096u;
    const unsigned offC = offA + 8192u;

    const char* wlane = (const char*)Wsw + cg * 131072 + lane * 16;

    // drain A-fragment loads so vmcnt counts ONLY the DMA stream from here on
    asm volatile("s_waitcnt vmcnt(0)" ::: "memory");
    STAGE(bufA, wlane);            // group 0
    STAGE(bufB, wlane + 4096);     // group 1

    // ---- K loop: 32 groups of 32 codes; compute g while g+1, g+2 DMAs fly
    unsigned kb = (unsigned)(cg * 1024 + l15);
    const char* wnext = wlane + 8192;
    #pragma unroll 1
    for (int it = 0; it < 10; ++it) {
        STAGE(bufC, wnext);            // group 3it+2
        VMWAIT(8);                     // group 3it resident
        BODY(offA, kb);
        STAGE(bufA, wnext + 4096);     // group 3it+3
        VMWAIT(8);                     // group 3it+1 resident
        BODY(offB, kb + 32u);
        STAGE(bufB, wnext + 8192);     // group 3it+4
        VMWAIT(8);                     // group 3it+2 resident
        BODY(offC, kb + 64u);
        wnext += 12288; kb += 96u;
    }
    // tail: groups 30 (bufA), 31 (bufB) — in flight: 8 then 4 DMAs
    VMWAIT(4);
    BODY(offA, kb);
    VMWAIT(0);
    BODY(offB, kb + 32u);

    // ---- reduce across the 16 code-columns (lane bits 0..3), publish per-wave mins
    #pragma unroll
    for (int mt = 0; mt < 4; ++mt)
        #pragma unroll
        for (int r = 0; r < 4; ++r) {
            unsigned int v = minpk[mt][r];
            #pragma unroll
            for (int m = 1; m < 16; m <<= 1) {
                unsigned int o = (unsigned int)__shfl_xor((int)v, m, 64);
                v = o < v ? o : v;
            }
            if (l15 == 0) pk_lds[cg * 64 + mt * 16 + lq * 4 + r] = v;
        }
    __syncthreads();

    // ---- epilogue: wave w owns rows w*16 .. w*16+15 (of the block's 64)
    const int rl  = cg * 16 + l15;        // 0..63
    unsigned int v0 = pk_lds[rl];
    unsigned int v1 = pk_lds[64 + rl];
    unsigned int v2 = pk_lds[128 + rl];
    unsigned int v3 = pk_lds[192 + rl];
    unsigned int vm = v0 < v1 ? v0 : v1;
    unsigned int vn = v2 < v3 ? v2 : v3;
    unsigned int idx = (vm < vn ? vm : vn) & 0xFFFu;

    const int row = rowbase + rl;
    float loss = 0.0f;
    #pragma unroll
    for (int h = 0; h < 2; ++h) {
        const floatx4* wp = (const floatx4*)(W + idx * 64 + h * 32 + lq * 8);
        const floatx4* zp = (const floatx4*)(z + row * 64 + h * 32 + lq * 8);
        floatx4* op = (floatx4*)(out + 1 + row * 64 + h * 32 + lq * 8);
        #pragma unroll
        for (int part = 0; part < 2; ++part) {
            floatx4 wv = wp[part];
            floatx4 zv = zp[part];
            op[part] = wv;
            #pragma unroll
            for (int j = 0; j < 4; ++j) {
                float d = zv[j] - wv[j];
                loss = fmaf(d, d, loss);
            }
        }
    }
    #pragma unroll
    for (int m = 1; m < 64; m <<= 1) loss += __shfl_xor(loss, m, 64);
    if (lane == 0) ls[cg] = loss;
    __syncthreads();
    if (tid == 0) {
        float t = (ls[0] + ls[1]) + (ls[2] + ls[3]);
        atomicAdd(out, t * (0.25f / 4194304.0f));
    }
}

extern "C" void kernel_launch(void* const* d_in, const int* in_sizes, int n_in,
                              void* d_out, int out_size, void* d_ws, size_t ws_size,
                              hipStream_t stream) {
    (void)in_sizes; (void)n_in; (void)out_size; (void)ws_size;
    const float* z = (const float*)d_in[0];
    const float* W = (const float*)d_in[1];
    unsigned short* Wsw = (unsigned short*)d_ws;     // 512 KB: bf16(-w), B-frag order
    float* out = (float*)d_out;

    vq_prep<<<128, 256, 0, stream>>>(W, Wsw, out);
    vq_main<<<1024, 256, 0, stream>>>(z, W, Wsw, out);
}